// Round 1
// baseline (1855.965 us; speedup 1.0000x reference)
//
#include <hip/hip_runtime.h>
#include <math.h>

#define D       256
#define NROWS   32768      // 8 * 4096
#define CODES   8192
#define BM      128
#define BN      128
#define BK      32
#define NSPLIT  4
#define SPLIT_C (CODES / NSPLIT)   // 2048
#define QOFF    8388608            // 8*4096*256 floats (quantize region)

// ---------------------------------------------------------------------------
// Kernel A: row squared-norms for x (32768 rows) and embed (8192 rows).
// One wave per row: 64 lanes x float4 = 256 floats exactly.
// ---------------------------------------------------------------------------
__global__ __launch_bounds__(256) void sq_kernel(const float* __restrict__ x,
                                                 const float* __restrict__ embed,
                                                 float* __restrict__ x2,
                                                 float* __restrict__ e2) {
  int wid  = threadIdx.x >> 6;
  int lane = threadIdx.x & 63;
  int rid  = blockIdx.x * 4 + wid;   // 0..40959
  const float* base = (rid < NROWS) ? (x + (size_t)rid * D)
                                    : (embed + (size_t)(rid - NROWS) * D);
  float4 v = *(const float4*)(base + lane * 4);
  float p = v.x * v.x + v.y * v.y + v.z * v.z + v.w * v.w;
  #pragma unroll
  for (int off = 32; off > 0; off >>= 1) p += __shfl_down(p, off);
  if (lane == 0) {
    if (rid < NROWS) x2[rid] = p;
    else             e2[rid - NROWS] = p;
  }
}

// ---------------------------------------------------------------------------
// Kernel B: fused GEMM + running argmax of dist = -sqrt(max(x2+e2-2*xe, 0)).
// Tile: BM=128 rows x BN=128 codes x BK=32. 256 threads (16x16), 8x8 microtile.
// Grid: (NROWS/BM) x NSPLIT. Each block scans SPLIT_C codes of one split.
// Partial (bestVal,bestIdx) per row per split written to scratch.
// ---------------------------------------------------------------------------
__global__ __launch_bounds__(256) void argmin_kernel(const float* __restrict__ x,
                                                     const float* __restrict__ embed,
                                                     const float* __restrict__ x2,
                                                     const float* __restrict__ e2,
                                                     float* __restrict__ pVal,
                                                     int* __restrict__ pIdx) {
  __shared__ float As[BK][BM];   // k-major: As[k][row]
  __shared__ float Bs[BK][BN];   // k-major: Bs[k][code]

  const int tid = threadIdx.x;
  const int ty = tid >> 4;          // 0..15 -> row group
  const int tx = tid & 15;          // 0..15 -> code group
  const int rowBase = blockIdx.x * BM;
  const int split = blockIdx.y;
  const int r0 = ty * 8;
  const int c0 = tx * 8;

  float bestV[8];
  int   bestI[8];
  #pragma unroll
  for (int i = 0; i < 8; i++) { bestV[i] = -INFINITY; bestI[i] = 0; }

  float x2r[8];
  #pragma unroll
  for (int i = 0; i < 8; i++) x2r[i] = x2[rowBase + r0 + i];

  for (int chunk = 0; chunk < SPLIT_C / BN; ++chunk) {
    const int cBase = split * SPLIT_C + chunk * BN;

    float acc[8][8];
    #pragma unroll
    for (int i = 0; i < 8; i++)
      #pragma unroll
      for (int j = 0; j < 8; j++) acc[i][j] = 0.0f;

    for (int kb = 0; kb < D / BK; ++kb) {
      // ---- stage A and B tiles (transposed to k-major) ----
      #pragma unroll
      for (int i = 0; i < 4; i++) {
        int f4 = tid + i * 256;        // 0..1023
        int rr = f4 >> 3;              // 0..127
        int k4 = f4 & 7;               // 0..7
        float4 va = *(const float4*)&x[(size_t)(rowBase + rr) * D + kb * BK + k4 * 4];
        As[k4 * 4 + 0][rr] = va.x;
        As[k4 * 4 + 1][rr] = va.y;
        As[k4 * 4 + 2][rr] = va.z;
        As[k4 * 4 + 3][rr] = va.w;
        float4 vb = *(const float4*)&embed[(size_t)(cBase + rr) * D + kb * BK + k4 * 4];
        Bs[k4 * 4 + 0][rr] = vb.x;
        Bs[k4 * 4 + 1][rr] = vb.y;
        Bs[k4 * 4 + 2][rr] = vb.z;
        Bs[k4 * 4 + 3][rr] = vb.w;
      }
      __syncthreads();

      // ---- compute ----
      #pragma unroll 8
      for (int kk = 0; kk < BK; kk++) {
        float a[8], b[8];
        *(float4*)&a[0] = *(const float4*)&As[kk][r0];
        *(float4*)&a[4] = *(const float4*)&As[kk][r0 + 4];
        *(float4*)&b[0] = *(const float4*)&Bs[kk][c0];
        *(float4*)&b[4] = *(const float4*)&Bs[kk][c0 + 4];
        #pragma unroll
        for (int i = 0; i < 8; i++)
          #pragma unroll
          for (int j = 0; j < 8; j++)
            acc[i][j] = fmaf(a[i], b[j], acc[i][j]);
      }
      __syncthreads();
    }

    // ---- epilogue: dist + running argmax (ascending c, strict >) ----
    #pragma unroll
    for (int j = 0; j < 8; j++) {
      int c = cBase + c0 + j;
      float e2c = e2[c];
      #pragma unroll
      for (int i = 0; i < 8; i++) {
        float s  = __fadd_rn(x2r[i], e2c);        // x2 + e2   (mirror ref order)
        float u  = __fmul_rn(2.0f, acc[i][j]);    // 2*xe
        float d2 = fmaxf(__fsub_rn(s, u), 0.0f);  // max(.., 0)
        float dist = -sqrtf(d2);
        if (dist > bestV[i]) { bestV[i] = dist; bestI[i] = c; }
      }
    }
  }

  // ---- cross-thread (tx) reduction via LDS; reuse tile memory ----
  __syncthreads();
  float* Vl = &As[0][0];       // 16*16*8 = 2048 floats (fits in As)
  int*   Il = (int*)&Bs[0][0];
  #pragma unroll
  for (int i = 0; i < 8; i++) {
    Vl[(ty * 16 + tx) * 8 + i] = bestV[i];
    Il[(ty * 16 + tx) * 8 + i] = bestI[i];
  }
  __syncthreads();

  if (tid < BM) {
    int rr  = tid;
    int tyr = rr >> 3;
    int ii  = rr & 7;
    float bv = -INFINITY;
    int   bi = 0;
    #pragma unroll
    for (int t = 0; t < 16; t++) {
      float v  = Vl[(tyr * 16 + t) * 8 + ii];
      int   iv = Il[(tyr * 16 + t) * 8 + ii];
      if (v > bv || (v == bv && iv < bi)) { bv = v; bi = iv; }
    }
    pVal[split * NROWS + rowBase + rr] = bv;
    pIdx[split * NROWS + rowBase + rr] = bi;
  }
}

// ---------------------------------------------------------------------------
// Kernel C: merge NSPLIT partials per row -> final index (as float32 value).
// Tie -> smaller index (global first-occurrence semantics).
// ---------------------------------------------------------------------------
__global__ __launch_bounds__(256) void merge_kernel(const float* __restrict__ pVal,
                                                    const int* __restrict__ pIdx,
                                                    float* __restrict__ indF) {
  int row = blockIdx.x * 256 + threadIdx.x;
  if (row >= NROWS) return;
  float bv = -INFINITY;
  int   bi = 0;
  #pragma unroll
  for (int s = 0; s < NSPLIT; s++) {
    float v  = pVal[s * NROWS + row];
    int   iv = pIdx[s * NROWS + row];
    if (v > bv || (v == bv && iv < bi)) { bv = v; bi = iv; }
  }
  indF[row] = (float)bi;
}

// ---------------------------------------------------------------------------
// Kernel D: gather quantize = embed[ind]. One wave per row, float4 lanes.
// ---------------------------------------------------------------------------
__global__ __launch_bounds__(256) void gather_kernel(const float* __restrict__ embed,
                                                     const float* __restrict__ indF,
                                                     float* __restrict__ outQ) {
  int wid  = threadIdx.x >> 6;
  int lane = threadIdx.x & 63;
  int row  = blockIdx.x * 4 + wid;   // 0..32767
  int idx  = (int)indF[row];
  float4 v = *(const float4*)&embed[(size_t)idx * D + lane * 4];
  *(float4*)&outQ[(size_t)row * D + lane * 4] = v;
}

// ---------------------------------------------------------------------------
extern "C" void kernel_launch(void* const* d_in, const int* in_sizes, int n_in,
                              void* d_out, int out_size, void* d_ws, size_t ws_size,
                              hipStream_t stream) {
  const float* x     = (const float*)d_in[0];   // [8,4096,256] fp32
  const float* embed = (const float*)d_in[1];   // [1,8192,256] fp32
  float* o = (float*)d_out;

  // Scratch layout inside the quantize region (overwritten by gather at the end):
  float* x2   = o;                    // 32768 floats
  float* e2   = o + 32768;            // 8192 floats
  float* pVal = o + 65536;            // NSPLIT*32768 floats
  int*   pIdx = (int*)(o + 196608);   // NSPLIT*32768 ints
  float* indF = o + QOFF;             // 32768 floats: final index output
  float* outQ = o;                    // quantize region [32768][256]

  // A: squared norms (40960 rows, 4 rows/block)
  sq_kernel<<<(NROWS + CODES) / 4, 256, 0, stream>>>(x, embed, x2, e2);

  // B: fused distance GEMM + partial argmax
  dim3 gridB(NROWS / BM, NSPLIT);
  argmin_kernel<<<gridB, 256, 0, stream>>>(x, embed, x2, e2, pVal, pIdx);

  // C: merge splits -> final indices
  merge_kernel<<<NROWS / 256, 256, 0, stream>>>(pVal, pIdx, indF);

  // D: gather codes
  gather_kernel<<<NROWS / 4, 256, 0, stream>>>(embed, indF, outQ);
}

// Round 2
// 822.706 us; speedup vs baseline: 2.2559x; 2.2559x over previous
//
#include <hip/hip_runtime.h>
#include <math.h>

#define D       256
#define NROWS   32768      // 8 * 4096
#define CODES   8192
#define QOFF    8388608    // quantize region floats

// ---------------- MFMA path config ----------------
#define BM      128
#define BN      128
#define NSPL    2
#define SPLC    (CODES / NSPL)    // 4096
#define NCHUNK  (SPLC / BN)       // 32
#define A3_ROWB 1536              // bytes per split row (768 bf16: h|m|l planes)

#define WS_A3   0ull
#define WS_PKEY 50331648ull                 // 32768*1536
#define WS_X2   (WS_PKEY + 524288ull)       // 2*32768*8
#define WS_E2   (WS_X2 + 131072ull)
#define WS_NEED (WS_E2 + 32768ull)          // ~51.0 MB

typedef __attribute__((ext_vector_type(8))) short bf16x8;
typedef __attribute__((ext_vector_type(4))) float f32x4;

// Involutive LDS swizzle: key = byte bits 8:7 (row bits 2:1), modifies bits 5:4.
// Makes ds_read_b128 of [row][64B] plane tiles 2-way (free) instead of 8-way.
__device__ __forceinline__ int SW(int b) { return b ^ (((b >> 7) & 3) << 4); }

__device__ __forceinline__ void gload16(const void* g, void* l) {
  __builtin_amdgcn_global_load_lds(
      (const __attribute__((address_space(1))) unsigned int*)g,
      (__attribute__((address_space(3))) unsigned int*)l, 16, 0, 0);
}

__device__ __forceinline__ unsigned short bf16rn(float x) {
  unsigned u = __float_as_uint(x);
  return (unsigned short)((u + 0x7fffu + ((u >> 16) & 1u)) >> 16);
}

// ---------------------------------------------------------------------------
// Shared: row squared-norms for x and embed (fp32, matches ref arithmetic).
// ---------------------------------------------------------------------------
__global__ __launch_bounds__(256) void sq_kernel(const float* __restrict__ x,
                                                 const float* __restrict__ embed,
                                                 float* __restrict__ x2,
                                                 float* __restrict__ e2) {
  int wid  = threadIdx.x >> 6;
  int lane = threadIdx.x & 63;
  int rid  = blockIdx.x * 4 + wid;
  const float* base = (rid < NROWS) ? (x + (size_t)rid * D)
                                    : (embed + (size_t)(rid - NROWS) * D);
  float4 v = *(const float4*)(base + lane * 4);
  float p = v.x * v.x + v.y * v.y + v.z * v.z + v.w * v.w;
  #pragma unroll
  for (int off = 32; off > 0; off >>= 1) p += __shfl_down(p, off);
  if (lane == 0) {
    if (rid < NROWS) x2[rid] = p;
    else             e2[rid - NROWS] = p;
  }
}

// ---------------------------------------------------------------------------
// MFMA path kernel 1: 3-way bf16 split of x and embed.
// Layout per row: [256 h][256 m][256 l] bf16.
// ---------------------------------------------------------------------------
__global__ __launch_bounds__(256) void split_kernel(const float* __restrict__ x,
                                                    const float* __restrict__ embed,
                                                    unsigned short* __restrict__ A3,
                                                    unsigned short* __restrict__ E3) {
  int wid  = threadIdx.x >> 6;
  int lane = threadIdx.x & 63;
  int rid  = blockIdx.x * 4 + wid;
  const float* src;
  unsigned short* dst;
  if (rid < NROWS) { src = x + (size_t)rid * D;            dst = A3 + (size_t)rid * 768; }
  else             { src = embed + (size_t)(rid - NROWS) * D; dst = E3 + (size_t)(rid - NROWS) * 768; }
  float4 v = *(const float4*)(src + lane * 4);
  float vv[4] = {v.x, v.y, v.z, v.w};
  unsigned short hs[4], ms[4], ls[4];
  #pragma unroll
  for (int j = 0; j < 4; j++) {
    float xx = vv[j];
    unsigned short hb = bf16rn(xx);
    float hf = __uint_as_float((unsigned)hb << 16);
    float r1 = __fsub_rn(xx, hf);
    unsigned short mb = bf16rn(r1);
    float mf = __uint_as_float((unsigned)mb << 16);
    float r2 = __fsub_rn(r1, mf);
    unsigned short lb = bf16rn(r2);
    hs[j] = hb; ms[j] = mb; ls[j] = lb;
  }
  *(ushort4*)(dst + lane * 4)       = make_ushort4(hs[0], hs[1], hs[2], hs[3]);
  *(ushort4*)(dst + 256 + lane * 4) = make_ushort4(ms[0], ms[1], ms[2], ms[3]);
  *(ushort4*)(dst + 512 + lane * 4) = make_ushort4(ls[0], ls[1], ls[2], ls[3]);
}

// ---------------------------------------------------------------------------
// MFMA path kernel 2: fused 6-term split-GEMM + running argmin on
// key = (bits(sqrt(d2)) << 32) | col   (min-u64 == ref argmax of -sqrt,
// first-occurrence tiebreak).
// Tile 128x128, 4 waves (2x2), per-wave 64x64 (4x4 fragments of 16x16x32).
// ---------------------------------------------------------------------------
__global__ __launch_bounds__(256, 2) void mfma_argmin_kernel(
    const unsigned short* __restrict__ A3,
    const unsigned short* __restrict__ E3,
    const float* __restrict__ x2,
    const float* __restrict__ e2,
    unsigned long long* __restrict__ pKey) {
  __shared__ __align__(16) char smem[49152];   // As 24KB | Bs 24KB (3 planes x 8KB)
  char* As = smem;
  char* Bs = smem + 24576;

  const int tid  = threadIdx.x;
  const int lane = tid & 63;
  const int wave = tid >> 6;
  const int wm = wave >> 1, wn = wave & 1;
  const int l15 = lane & 15, lh = lane >> 4;
  const int rowBase = blockIdx.x * BM;
  const int split   = blockIdx.y;

  // Fragment LDS byte offsets within a plane (constant all iterations)
  int swA[4], swB[4];
  #pragma unroll
  for (int f = 0; f < 4; f++) {
    int rowA = wm * 64 + f * 16 + l15;
    swA[f] = SW((rowA << 6) | (lh << 4));
    int rowB = wn * 64 + f * 16 + l15;
    swB[f] = SW((rowB << 6) | (lh << 4));
  }

  // Staging constants: 6 global_load_lds insts each for A and B per k-chunk.
  int stRow[6], stPO[6];     // row within tile; plane*512 + rest (source byte off)
  char* stDstA[6]; char* stDstB[6];
  #pragma unroll
  for (int i = 0; i < 6; i++) {
    int s = i * 256 + tid;         // 0..1535 lane-slot
    int plane = s >> 9;
    int q = s & 511;
    int u = SW(q << 4);            // logical byte this slot must hold (involution)
    stRow[i] = u >> 6;
    stPO[i]  = plane * 512 + (u & 63);
    stDstA[i] = As + plane * 8192 + (q & ~63) * 16;
    stDstB[i] = Bs + plane * 8192 + (q & ~63) * 16;
  }

  unsigned long long bestK[16];
  #pragma unroll
  for (int i = 0; i < 16; i++) bestK[i] = ~0ull;

  for (int cc = 0; cc < NCHUNK; ++cc) {
    const int cBase = split * SPLC + cc * BN;

    f32x4 acc[4][4];
    #pragma unroll
    for (int i = 0; i < 4; i++)
      #pragma unroll
      for (int j = 0; j < 4; j++) acc[i][j] = (f32x4)(0.0f);

    for (int kb = 0; kb < 8; ++kb) {
      __syncthreads();
      #pragma unroll
      for (int i = 0; i < 6; i++) {
        const char* srcA = (const char*)A3 + (size_t)(rowBase + stRow[i]) * A3_ROWB
                         + stPO[i] + kb * 64;
        gload16(srcA, stDstA[i]);
        const char* srcB = (const char*)E3 + (size_t)(cBase + stRow[i]) * A3_ROWB
                         + stPO[i] + kb * 64;
        gload16(srcB, stDstB[i]);
      }
      __syncthreads();

      // All A fragments (3 planes x 4 m-frags), held across B groups.
      bf16x8 af[3][4];
      #pragma unroll
      for (int p = 0; p < 3; p++)
        #pragma unroll
        for (int f = 0; f < 4; f++)
          af[p][f] = *(const bf16x8*)(As + p * 8192 + swA[f]);

      // pb = H: h·H + m·H + l·H
      {
        bf16x8 bf[4];
        #pragma unroll
        for (int f = 0; f < 4; f++) bf[f] = *(const bf16x8*)(Bs + swB[f]);
        #pragma unroll
        for (int fm = 0; fm < 4; fm++)
          #pragma unroll
          for (int fn = 0; fn < 4; fn++) {
            acc[fm][fn] = __builtin_amdgcn_mfma_f32_16x16x32_bf16(af[0][fm], bf[fn], acc[fm][fn], 0, 0, 0);
            acc[fm][fn] = __builtin_amdgcn_mfma_f32_16x16x32_bf16(af[1][fm], bf[fn], acc[fm][fn], 0, 0, 0);
            acc[fm][fn] = __builtin_amdgcn_mfma_f32_16x16x32_bf16(af[2][fm], bf[fn], acc[fm][fn], 0, 0, 0);
          }
      }
      // pb = M: h·M + m·M
      {
        bf16x8 bf[4];
        #pragma unroll
        for (int f = 0; f < 4; f++) bf[f] = *(const bf16x8*)(Bs + 8192 + swB[f]);
        #pragma unroll
        for (int fm = 0; fm < 4; fm++)
          #pragma unroll
          for (int fn = 0; fn < 4; fn++) {
            acc[fm][fn] = __builtin_amdgcn_mfma_f32_16x16x32_bf16(af[0][fm], bf[fn], acc[fm][fn], 0, 0, 0);
            acc[fm][fn] = __builtin_amdgcn_mfma_f32_16x16x32_bf16(af[1][fm], bf[fn], acc[fm][fn], 0, 0, 0);
          }
      }
      // pb = L: h·L
      {
        bf16x8 bf[4];
        #pragma unroll
        for (int f = 0; f < 4; f++) bf[f] = *(const bf16x8*)(Bs + 16384 + swB[f]);
        #pragma unroll
        for (int fm = 0; fm < 4; fm++)
          #pragma unroll
          for (int fn = 0; fn < 4; fn++)
            acc[fm][fn] = __builtin_amdgcn_mfma_f32_16x16x32_bf16(af[0][fm], bf[fn], acc[fm][fn], 0, 0, 0);
      }
    }

    // Epilogue: d2 -> sqrt -> packed running min (ascending cc/col order).
    #pragma unroll
    for (int fn = 0; fn < 4; fn++) {
      int col = cBase + wn * 64 + fn * 16 + l15;
      float e2c = e2[col];
      #pragma unroll
      for (int fm = 0; fm < 4; fm++) {
        #pragma unroll
        for (int r = 0; r < 4; r++) {
          int row = rowBase + wm * 64 + fm * 16 + lh * 4 + r;
          float s  = __fadd_rn(x2[row], e2c);
          float d2 = __fsub_rn(s, __fmul_rn(2.0f, acc[fm][fn][r]));
          d2 = fmaxf(d2, 0.0f);
          float sq = sqrtf(d2);
          unsigned long long key =
              ((unsigned long long)__float_as_uint(sq) << 32) | (unsigned)col;
          int slot = fm * 4 + r;
          if (key < bestK[slot]) bestK[slot] = key;
        }
      }
    }
  }

  // Reduce across the 16 lanes sharing each row (cols), tie -> smaller col.
  #pragma unroll
  for (int slot = 0; slot < 16; slot++) {
    #pragma unroll
    for (int off = 1; off < 16; off <<= 1) {
      unsigned long long o = __shfl_xor(bestK[slot], off);
      if (o < bestK[slot]) bestK[slot] = o;
    }
  }

  // Combine the two wn halves via LDS, write per-row key.
  __syncthreads();
  unsigned long long* red = (unsigned long long*)smem;  // [2][128]
  if (l15 == 0) {
    #pragma unroll
    for (int fm = 0; fm < 4; fm++)
      #pragma unroll
      for (int r = 0; r < 4; r++) {
        int rloc = wm * 64 + fm * 16 + lh * 4 + r;
        red[wn * 128 + rloc] = bestK[fm * 4 + r];
      }
  }
  __syncthreads();
  if (tid < 128) {
    unsigned long long a = red[tid], b = red[128 + tid];
    pKey[(size_t)split * NROWS + rowBase + tid] = (a < b) ? a : b;
  }
}

// ---------------------------------------------------------------------------
// MFMA path kernel 3: merge 2 splits, gather codes, write index as float.
// ---------------------------------------------------------------------------
__global__ __launch_bounds__(256) void finalize_kernel(const float* __restrict__ embed,
                                                       const unsigned long long* __restrict__ pKey,
                                                       float* __restrict__ outQ,
                                                       float* __restrict__ indF) {
  int wid  = threadIdx.x >> 6;
  int lane = threadIdx.x & 63;
  int row  = blockIdx.x * 4 + wid;
  unsigned long long a = pKey[row], b = pKey[NROWS + row];
  unsigned long long m = (a < b) ? a : b;
  int idx = (int)(unsigned)(m & 0xffffffffull);
  float4 v = *(const float4*)&embed[(size_t)idx * D + lane * 4];
  *(float4*)&outQ[(size_t)row * D + lane * 4] = v;
  if (lane == 0) indF[row] = (float)idx;
}

// ===========================================================================
// Fallback fp32 path (round-1, passes exactly) — used if ws_size < WS_NEED.
// ===========================================================================
#define BM_F 128
#define BN_F 128
#define BK_F 32
#define NSPLIT_F 4
#define SPLIT_CF (CODES / NSPLIT_F)

__global__ __launch_bounds__(256) void argmin_f32_kernel(const float* __restrict__ x,
                                                         const float* __restrict__ embed,
                                                         const float* __restrict__ x2,
                                                         const float* __restrict__ e2,
                                                         float* __restrict__ pVal,
                                                         int* __restrict__ pIdx) {
  __shared__ float As[BK_F][BM_F];
  __shared__ float Bs[BK_F][BN_F];
  const int tid = threadIdx.x;
  const int ty = tid >> 4, tx = tid & 15;
  const int rowBase = blockIdx.x * BM_F;
  const int split = blockIdx.y;
  const int r0 = ty * 8, c0 = tx * 8;
  float bestV[8]; int bestI[8];
  #pragma unroll
  for (int i = 0; i < 8; i++) { bestV[i] = -INFINITY; bestI[i] = 0; }
  float x2r[8];
  #pragma unroll
  for (int i = 0; i < 8; i++) x2r[i] = x2[rowBase + r0 + i];
  for (int chunk = 0; chunk < SPLIT_CF / BN_F; ++chunk) {
    const int cBase = split * SPLIT_CF + chunk * BN_F;
    float acc[8][8];
    #pragma unroll
    for (int i = 0; i < 8; i++)
      #pragma unroll
      for (int j = 0; j < 8; j++) acc[i][j] = 0.0f;
    for (int kb = 0; kb < D / BK_F; ++kb) {
      #pragma unroll
      for (int i = 0; i < 4; i++) {
        int f4 = tid + i * 256;
        int rr = f4 >> 3, k4 = f4 & 7;
        float4 va = *(const float4*)&x[(size_t)(rowBase + rr) * D + kb * BK_F + k4 * 4];
        As[k4 * 4 + 0][rr] = va.x; As[k4 * 4 + 1][rr] = va.y;
        As[k4 * 4 + 2][rr] = va.z; As[k4 * 4 + 3][rr] = va.w;
        float4 vb = *(const float4*)&embed[(size_t)(cBase + rr) * D + kb * BK_F + k4 * 4];
        Bs[k4 * 4 + 0][rr] = vb.x; Bs[k4 * 4 + 1][rr] = vb.y;
        Bs[k4 * 4 + 2][rr] = vb.z; Bs[k4 * 4 + 3][rr] = vb.w;
      }
      __syncthreads();
      #pragma unroll 8
      for (int kk = 0; kk < BK_F; kk++) {
        float a[8], b[8];
        *(float4*)&a[0] = *(const float4*)&As[kk][r0];
        *(float4*)&a[4] = *(const float4*)&As[kk][r0 + 4];
        *(float4*)&b[0] = *(const float4*)&Bs[kk][c0];
        *(float4*)&b[4] = *(const float4*)&Bs[kk][c0 + 4];
        #pragma unroll
        for (int i = 0; i < 8; i++)
          #pragma unroll
          for (int j = 0; j < 8; j++)
            acc[i][j] = fmaf(a[i], b[j], acc[i][j]);
      }
      __syncthreads();
    }
    #pragma unroll
    for (int j = 0; j < 8; j++) {
      int c = cBase + c0 + j;
      float e2c = e2[c];
      #pragma unroll
      for (int i = 0; i < 8; i++) {
        float s  = __fadd_rn(x2r[i], e2c);
        float u  = __fmul_rn(2.0f, acc[i][j]);
        float d2 = fmaxf(__fsub_rn(s, u), 0.0f);
        float dist = -sqrtf(d2);
        if (dist > bestV[i]) { bestV[i] = dist; bestI[i] = c; }
      }
    }
  }
  __syncthreads();
  float* Vl = &As[0][0];
  int*   Il = (int*)&Bs[0][0];
  #pragma unroll
  for (int i = 0; i < 8; i++) {
    Vl[(ty * 16 + tx) * 8 + i] = bestV[i];
    Il[(ty * 16 + tx) * 8 + i] = bestI[i];
  }
  __syncthreads();
  if (tid < BM_F) {
    int rr = tid, tyr = rr >> 3, ii = rr & 7;
    float bv = -INFINITY; int bi = 0;
    #pragma unroll
    for (int t = 0; t < 16; t++) {
      float v = Vl[(tyr * 16 + t) * 8 + ii];
      int  iv = Il[(tyr * 16 + t) * 8 + ii];
      if (v > bv || (v == bv && iv < bi)) { bv = v; bi = iv; }
    }
    pVal[split * NROWS + rowBase + rr] = bv;
    pIdx[split * NROWS + rowBase + rr] = bi;
  }
}

__global__ __launch_bounds__(256) void merge_f32_kernel(const float* __restrict__ pVal,
                                                        const int* __restrict__ pIdx,
                                                        float* __restrict__ indF) {
  int row = blockIdx.x * 256 + threadIdx.x;
  if (row >= NROWS) return;
  float bv = -INFINITY; int bi = 0;
  #pragma unroll
  for (int s = 0; s < NSPLIT_F; s++) {
    float v = pVal[s * NROWS + row];
    int  iv = pIdx[s * NROWS + row];
    if (v > bv || (v == bv && iv < bi)) { bv = v; bi = iv; }
  }
  indF[row] = (float)bi;
}

__global__ __launch_bounds__(256) void gather_f32_kernel(const float* __restrict__ embed,
                                                         const float* __restrict__ indF,
                                                         float* __restrict__ outQ) {
  int wid = threadIdx.x >> 6, lane = threadIdx.x & 63;
  int row = blockIdx.x * 4 + wid;
  int idx = (int)indF[row];
  float4 v = *(const float4*)&embed[(size_t)idx * D + lane * 4];
  *(float4*)&outQ[(size_t)row * D + lane * 4] = v;
}

// ---------------------------------------------------------------------------
extern "C" void kernel_launch(void* const* d_in, const int* in_sizes, int n_in,
                              void* d_out, int out_size, void* d_ws, size_t ws_size,
                              hipStream_t stream) {
  const float* x     = (const float*)d_in[0];
  const float* embed = (const float*)d_in[1];
  float* o = (float*)d_out;

  if (ws_size >= WS_NEED) {
    // ---- MFMA split path ----
    unsigned short* A3 = (unsigned short*)((char*)d_ws + WS_A3);
    unsigned long long* pKey = (unsigned long long*)((char*)d_ws + WS_PKEY);
    float* x2 = (float*)((char*)d_ws + WS_X2);
    float* e2 = (float*)((char*)d_ws + WS_E2);
    unsigned short* E3 = (unsigned short*)o;   // 12.6 MB in quantize region
    float* indF = o + QOFF;

    split_kernel<<<(NROWS + CODES) / 4, 256, 0, stream>>>(x, embed, A3, E3);
    sq_kernel<<<(NROWS + CODES) / 4, 256, 0, stream>>>(x, embed, x2, e2);
    dim3 gridB(NROWS / BM, NSPL);
    mfma_argmin_kernel<<<gridB, 256, 0, stream>>>(A3, E3, x2, e2, pKey);
    finalize_kernel<<<NROWS / 4, 256, 0, stream>>>(embed, pKey, o, indF);
  } else {
    // ---- fp32 fallback (round-1) ----
    float* x2   = o;
    float* e2   = o + 32768;
    float* pVal = o + 65536;
    int*   pIdx = (int*)(o + 196608);
    float* indF = o + QOFF;

    sq_kernel<<<(NROWS + CODES) / 4, 256, 0, stream>>>(x, embed, x2, e2);
    dim3 gridB(NROWS / BM_F, NSPLIT_F);
    argmin_f32_kernel<<<gridB, 256, 0, stream>>>(x, embed, x2, e2, pVal, pIdx);
    merge_f32_kernel<<<NROWS / 256, 256, 0, stream>>>(pVal, pIdx, indF);
    gather_f32_kernel<<<NROWS / 4, 256, 0, stream>>>(embed, indF, o);
  }
}